// Round 4
// baseline (132.107 us; speedup 1.0000x reference)
//
#include <hip/hip_runtime.h>
#include <math.h>

#define TLEN 4096
#define NB   1024
#define NS   10

typedef float f32x4 __attribute__((ext_vector_type(4)));

// ---------------- KA: S partials + embedded k0 ------------------------------
// S[n,p,t] = sum_b SA[b,p,n]*x[t,b,n];  ps layout: ps[(sl*100+n*10+p)*4096 + t]
#define TB   32    // t per block
#define BSL  128   // b per slice (8 slices)
#define BC   16    // b chunk staged in LDS
#define XSTR 166   // xs row stride (words); 166 mod 32 = 6 -> 2-way on reads

__device__ void k0_body(const float* __restrict__ adj, float* __restrict__ ck) {
  float Wm[5][5], L[5][5];
  for (int r = 0; r < 5; ++r)
    for (int c = 0; c < 5; ++c) Wm[r][c] = adj[r*5+c];
  for (int r = 0; r < 5; ++r) {
    float d = 0.f;
    for (int c = 0; c < 5; ++c) d += Wm[r][c];
    for (int c = 0; c < 5; ++c) L[r][c] = (r==c ? d : 0.f) - Wm[r][c];
  }
  float v[5] = {0.7f, -1.1f, 0.9f, -0.8f, 1.3f};
  for (int it = 0; it < 96; ++it) {
    float w[5];
    for (int r = 0; r < 5; ++r) {
      float s = 0.f;
      for (int c = 0; c < 5; ++c) s += L[r][c]*v[c];
      w[r] = s;
    }
    float s = fabsf(w[0])+fabsf(w[1])+fabsf(w[2])+fabsf(w[3])+fabsf(w[4]);
    float inv = 1.f/s;
    for (int r = 0; r < 5; ++r) v[r] = w[r]*inv;
  }
  float num = 0.f, den = 0.f;
  for (int r = 0; r < 5; ++r) {
    float s = 0.f;
    for (int c = 0; c < 5; ++c) s += L[r][c]*v[c];
    num += v[r]*s; den += v[r]*v[r];
  }
  const float lam = num/den;
  float Lt[5][5];
  for (int r = 0; r < 5; ++r)
    for (int c = 0; c < 5; ++c)
      Lt[r][c] = 2.f*L[r][c]/lam - (r==c ? 1.f : 0.f);
  float T2[5][5];
  for (int r = 0; r < 5; ++r)
    for (int c = 0; c < 5; ++c) {
      float s = 0.f;
      for (int j = 0; j < 5; ++j) s += Lt[r][j]*Lt[j][c];
      T2[r][c] = 2.f*s - (r==c ? 1.f : 0.f);
    }
  for (int p = 0; p < 10; ++p)
    for (int n = 0; n < 10; ++n) {
      int m = (10*p+n) % 25, r = m/5, c = m%5;
      ck[0*100 + p*10+n] = (r==c ? 1.f : 0.f);
      ck[1*100 + p*10+n] = Lt[r][c];
      ck[2*100 + p*10+n] = T2[r][c];
    }
}

__global__ __launch_bounds__(384) void ka_reduce(const float* __restrict__ x,
    const float* __restrict__ sa, const float* __restrict__ adj,
    float* __restrict__ ps, float* __restrict__ ck) {
  __shared__ __align__(16) float xs[TB*XSTR];     // 21.2 KB
  __shared__ __align__(16) float sas[BC*120];     // [bb][n][12] padded, 7.7 KB
  const int tid = threadIdx.x;
  if (tid >= 320) {                 // 6th wave: k0 in block (0,0), else exit
    if (tid == 320 && blockIdx.x == 0 && blockIdx.y == 0) k0_body(adj, ck);
    return;
  }
  const int n  = tid >> 5;   // 0..9
  const int t  = tid & 31;   // 0..31
  const int t0 = blockIdx.x * TB;
  const int bbase = blockIdx.y * BSL;

  const int stt = tid / 40;          // 0..7
  const int sq  = tid - stt*40;      // 0..39
  int saw0[4], saw1[4];
  {
    #pragma unroll
    for (int e = 0; e < 4; ++e) {
      const int g = tid*4 + e, bb = g/100, r = g - bb*100, p = r/10, nn = r - p*10;
      saw0[e] = bb*120 + nn*12 + p;
    }
    #pragma unroll
    for (int e = 0; e < 4; ++e) {
      const int g = (tid+320)*4 + e, bb = g/100, r = g - bb*100, p = r/10, nn = r - p*10;
      saw1[e] = bb*120 + nn*12 + p;
    }
  }

  float acc[10];
  #pragma unroll
  for (int p = 0; p < 10; ++p) acc[p] = 0.f;

  for (int cch = 0; cch < BSL/BC; ++cch) {
    const int bch = bbase + cch*BC;
    // stage x[t0..t0+32][bch..bch+16][:] -> xs[t][bb*10+n], 4 float4/thread
    #pragma unroll
    for (int r = 0; r < 4; ++r) {
      const int tt = stt + 8*r;
      const f32x4 v = __builtin_nontemporal_load(
          (const f32x4*)(x + (size_t)(t0+tt)*(NB*NS) + (size_t)bch*NS + sq*4));
      float2* w = (float2*)(xs + tt*XSTR + sq*4);
      w[0] = make_float2(v.x, v.y);
      w[1] = make_float2(v.z, v.w);
    }
    // stage SA[bch..bch+16][p][n] -> sas[bb][n][12]+p (transposed)
    {
      const float4 v = *(const float4*)(sa + (size_t)bch*100 + (size_t)tid*4);
      sas[saw0[0]] = v.x; sas[saw0[1]] = v.y;
      sas[saw0[2]] = v.z; sas[saw0[3]] = v.w;
      if (tid < 80) {
        const float4 v2 = *(const float4*)(sa + (size_t)bch*100 + (size_t)(tid+320)*4);
        sas[saw1[0]] = v2.x; sas[saw1[1]] = v2.y;
        sas[saw1[2]] = v2.z; sas[saw1[3]] = v2.w;
      }
    }
    __syncthreads();
    const float* xrow = xs + t*XSTR + n;
    #pragma unroll
    for (int bb = 0; bb < BC; ++bb) {
      const float xv = xrow[bb*NS];
      const float* sp = sas + bb*120 + n*12;
      const float4 sA = *(const float4*)(sp);
      const float4 sB = *(const float4*)(sp + 4);
      const float2 sC = *(const float2*)(sp + 8);
      acc[0] += sA.x*xv; acc[1] += sA.y*xv;
      acc[2] += sA.z*xv; acc[3] += sA.w*xv;
      acc[4] += sB.x*xv; acc[5] += sB.y*xv;
      acc[6] += sB.z*xv; acc[7] += sB.w*xv;
      acc[8] += sC.x*xv; acc[9] += sC.y*xv;
    }
    __syncthreads();
  }
  // ps[(sl*100 + n*10 + p)*4096 + t0 + t] — coalesced over t
  {
    float* d0 = ps + (((size_t)blockIdx.y*100 + n*10) << 12) + t0 + t;
    #pragma unroll
    for (int p = 0; p < 10; ++p) d0[(size_t)p << 12] = acc[p];
  }
}

// ---------------- KC: out[t,b,n] = relu( sum_p S[n,p,t] * W[p,n,b] ) -------
#define TT 8
__global__ __launch_bounds__(256) void kc_out(const float* __restrict__ theta,
    const float* __restrict__ ck, const float* __restrict__ ps,
    float* __restrict__ out) {
  __shared__ __align__(16) float S[TT*120];     // [tt][n][12] padded
  __shared__ float C[300];
  __shared__ __align__(16) float stg[2][2560];  // double-buffered store stage
  const int tid = threadIdx.x;
  const int t0 = blockIdx.x * TT;
  const int b  = blockIdx.y * 256 + tid;
  for (int j = tid; j < 300; j += 256) C[j] = ck[j];
  for (int jj = tid; jj < TT*100; jj += 256) {
    const int q = jj >> 3, tt = jj & 7;
    float s = 0.f;
    #pragma unroll
    for (int sl = 0; sl < 8; ++sl)
      s += ps[(((size_t)sl*100 + q) << 12) + t0 + tt];
    S[tt*120 + (q/10)*12 + (q - (q/10)*10)] = s;
  }
  __syncthreads();
  float W[10][10];
  #pragma unroll
  for (int p = 0; p < 10; ++p) {
    const float th0 = theta[          p*NB + b];
    const float th1 = theta[10*NB  +  p*NB + b];
    const float th2 = theta[20*NB  +  p*NB + b];
    #pragma unroll
    for (int nn = 0; nn < 10; ++nn)
      W[p][nn] = C[p*10+nn]*th0 + C[100+p*10+nn]*th1 + C[200+p*10+nn]*th2;
  }
  for (int tt = 0; tt < TT; ++tt) {
    float acc[10];
    #pragma unroll
    for (int nn = 0; nn < 10; ++nn) {
      const float4 s0 = *(const float4*)(S + tt*120 + nn*12);
      const float4 s1 = *(const float4*)(S + tt*120 + nn*12 + 4);
      const float2 s2 = *(const float2*)(S + tt*120 + nn*12 + 8);
      acc[nn] = s0.x*W[0][nn] + s0.y*W[1][nn] + s0.z*W[2][nn] + s0.w*W[3][nn]
              + s1.x*W[4][nn] + s1.y*W[5][nn] + s1.z*W[6][nn] + s1.w*W[7][nn]
              + s2.x*W[8][nn] + s2.y*W[9][nn];
    }
    float* sg = stg[tt & 1];
    #pragma unroll
    for (int nn = 0; nn < 10; ++nn)
      sg[tid*10 + nn] = fmaxf(acc[nn], 0.f);
    __syncthreads();
    const f32x4* sp = (const f32x4*)sg;
    f32x4* op = (f32x4*)(out + (size_t)(t0+tt)*(NB*NS)
                             + (size_t)blockIdx.y*2560);
    __builtin_nontemporal_store(sp[tid],       op + tid);
    __builtin_nontemporal_store(sp[tid + 256], op + tid + 256);
    if (tid < 128) __builtin_nontemporal_store(sp[tid + 512], op + tid + 512);
  }
}

extern "C" void kernel_launch(void* const* d_in, const int* in_sizes, int n_in,
                              void* d_out, int out_size, void* d_ws, size_t ws_size,
                              hipStream_t stream) {
  const float* x   = (const float*)d_in[0];  // (4096,1024,10)
  const float* adj = (const float*)d_in[1];  // (5,5)
  const float* sa  = (const float*)d_in[2];  // (1024,10,10)
  const float* th  = (const float*)d_in[3];  // (3,10,1024)
  float* out = (float*)d_out;
  float* ws  = (float*)d_ws;
  float* ck  = ws;                // 300 floats
  float* ps  = ws + 1024;         // 8*4096*100 floats = 13.1 MB
  hipLaunchKernelGGL(ka_reduce, dim3(TLEN/TB, 8), dim3(384), 0, stream,
                     x, sa, adj, ps, ck);
  hipLaunchKernelGGL(kc_out,    dim3(TLEN/TT, NB/256), dim3(256), 0, stream,
                     th, ck, ps, out);
}

// Round 5
// 107.182 us; speedup vs baseline: 1.2326x; 1.2326x over previous
//
#include <hip/hip_runtime.h>
#include <math.h>

#define TLEN 4096
#define NB   1024
#define NS   10

// ---------------- KA: S partials + embedded k0 ------------------------------
// S[n,p,t] = sum_b SA[b,p,n]*x[t,b,n];  ps layout: ps[(sl*4096 + t)*100 + n*10+p]
#define TB   64    // t per block
#define BSL  128   // b per slice (8 slices)
#define BC   16    // b chunk staged in LDS
#define XSTR 166   // xs row stride (words); read lane-stride 6 mod 32 -> ~2-way

__device__ void k0_body(const float* __restrict__ adj, float* __restrict__ ck) {
  float Wm[5][5], L[5][5];
  for (int r = 0; r < 5; ++r)
    for (int c = 0; c < 5; ++c) Wm[r][c] = adj[r*5+c];
  for (int r = 0; r < 5; ++r) {
    float d = 0.f;
    for (int c = 0; c < 5; ++c) d += Wm[r][c];
    for (int c = 0; c < 5; ++c) L[r][c] = (r==c ? d : 0.f) - Wm[r][c];
  }
  float v[5] = {0.7f, -1.1f, 0.9f, -0.8f, 1.3f};
  for (int it = 0; it < 96; ++it) {
    float w[5];
    for (int r = 0; r < 5; ++r) {
      float s = 0.f;
      for (int c = 0; c < 5; ++c) s += L[r][c]*v[c];
      w[r] = s;
    }
    float s = fabsf(w[0])+fabsf(w[1])+fabsf(w[2])+fabsf(w[3])+fabsf(w[4]);
    float inv = 1.f/s;
    for (int r = 0; r < 5; ++r) v[r] = w[r]*inv;
  }
  float num = 0.f, den = 0.f;
  for (int r = 0; r < 5; ++r) {
    float s = 0.f;
    for (int c = 0; c < 5; ++c) s += L[r][c]*v[c];
    num += v[r]*s; den += v[r]*v[r];
  }
  const float lam = num/den;
  float Lt[5][5];
  for (int r = 0; r < 5; ++r)
    for (int c = 0; c < 5; ++c)
      Lt[r][c] = 2.f*L[r][c]/lam - (r==c ? 1.f : 0.f);
  float T2[5][5];
  for (int r = 0; r < 5; ++r)
    for (int c = 0; c < 5; ++c) {
      float s = 0.f;
      for (int j = 0; j < 5; ++j) s += Lt[r][j]*Lt[j][c];
      T2[r][c] = 2.f*s - (r==c ? 1.f : 0.f);
    }
  for (int p = 0; p < 10; ++p)
    for (int n = 0; n < 10; ++n) {
      int m = (10*p+n) % 25, r = m/5, c = m%5;
      ck[0*100 + p*10+n] = (r==c ? 1.f : 0.f);
      ck[1*100 + p*10+n] = Lt[r][c];
      ck[2*100 + p*10+n] = T2[r][c];
    }
}

__global__ __launch_bounds__(384) void ka_reduce(const float* __restrict__ x,
    const float* __restrict__ sa, const float* __restrict__ adj,
    float* __restrict__ ps, float* __restrict__ ck) {
  __shared__ __align__(16) float xs[TB*XSTR];     // 42.5 KB
  __shared__ __align__(16) float sas[BC*120];     // [bb][n][12] padded, 7.7 KB
  const int tid = threadIdx.x;
  if (tid >= 320) {                 // 6th wave: k0 in block (0,0), else exit
    if (tid == 320 && blockIdx.x == 0 && blockIdx.y == 0) k0_body(adj, ck);
    return;
  }
  const int n  = tid >> 5;          // 0..9
  const int h  = (tid >> 4) & 1;    // bb-half
  const int tg = tid & 15;          // t-group; owns t = tg + 16j, j=0..3
  const int t0 = blockIdx.x * TB;
  const int bbase = blockIdx.y * BSL;

  const int stt = tid / 40;          // 0..7
  const int sq  = tid - stt*40;      // 0..39
  int saw0[4], saw1[4];
  {
    #pragma unroll
    for (int e = 0; e < 4; ++e) {
      const int g = tid*4 + e, bb = g/100, r = g - bb*100, p = r/10, nn = r - p*10;
      saw0[e] = bb*120 + nn*12 + p;
    }
    #pragma unroll
    for (int e = 0; e < 4; ++e) {
      const int g = (tid+320)*4 + e, bb = g/100, r = g - bb*100, p = r/10, nn = r - p*10;
      saw1[e] = bb*120 + nn*12 + p;
    }
  }

  float acc[4][10];
  #pragma unroll
  for (int j = 0; j < 4; ++j)
    #pragma unroll
    for (int p = 0; p < 10; ++p) acc[j][p] = 0.f;

  for (int cch = 0; cch < BSL/BC; ++cch) {
    const int bch = bbase + cch*BC;
    // stage x[t0..t0+64][bch..bch+16][:] -> xs[t][bb*10+nn], 8 float4/thread
    #pragma unroll
    for (int r = 0; r < 8; ++r) {
      const int tt = stt + 8*r;
      const float4 v = *(const float4*)(x + (size_t)(t0+tt)*(NB*NS)
                                          + (size_t)bch*NS + sq*4);
      float2* w = (float2*)(xs + tt*XSTR + sq*4);
      w[0] = make_float2(v.x, v.y);
      w[1] = make_float2(v.z, v.w);
    }
    // stage SA[bch..bch+16][p][nn] -> sas[bb][nn][12]+p (transposed)
    {
      const float4 v = *(const float4*)(sa + (size_t)bch*100 + (size_t)tid*4);
      sas[saw0[0]] = v.x; sas[saw0[1]] = v.y;
      sas[saw0[2]] = v.z; sas[saw0[3]] = v.w;
      if (tid < 80) {
        const float4 v2 = *(const float4*)(sa + (size_t)bch*100 + (size_t)(tid+320)*4);
        sas[saw1[0]] = v2.x; sas[saw1[1]] = v2.y;
        sas[saw1[2]] = v2.z; sas[saw1[3]] = v2.w;
      }
    }
    __syncthreads();
    #pragma unroll
    for (int bb8 = 0; bb8 < 8; ++bb8) {
      const int bb = h*8 + bb8;
      const float* sp = sas + bb*120 + n*12;
      const float4 sA = *(const float4*)(sp);
      const float4 sB = *(const float4*)(sp + 4);
      const float2 sC = *(const float2*)(sp + 8);
      float xv[4];
      #pragma unroll
      for (int j = 0; j < 4; ++j)
        xv[j] = xs[(tg + 16*j)*XSTR + bb*NS + n];
      #pragma unroll
      for (int j = 0; j < 4; ++j) {
        acc[j][0] += sA.x*xv[j]; acc[j][1] += sA.y*xv[j];
        acc[j][2] += sA.z*xv[j]; acc[j][3] += sA.w*xv[j];
        acc[j][4] += sB.x*xv[j]; acc[j][5] += sB.y*xv[j];
        acc[j][6] += sB.z*xv[j]; acc[j][7] += sB.w*xv[j];
        acc[j][8] += sC.x*xv[j]; acc[j][9] += sC.y*xv[j];
      }
    }
    __syncthreads();
  }
  // cross-half reduction: h=1 parks partials in xs, h=0 adds and stores
  if (h) {
    float* d = xs + (n*16 + tg)*40;
    #pragma unroll
    for (int j = 0; j < 4; ++j)
      #pragma unroll
      for (int p = 0; p < 10; ++p) d[j*10+p] = acc[j][p];
  }
  __syncthreads();
  if (!h) {
    const float* d = xs + (n*16 + tg)*40;
    #pragma unroll
    for (int j = 0; j < 4; ++j) {
      float* o = ps + ((size_t)blockIdx.y*TLEN + t0 + tg + 16*j)*100 + n*10;
      #pragma unroll
      for (int p = 0; p < 10; ++p) o[p] = acc[j][p] + d[j*10+p];
    }
  }
}

// ---------------- KC: out[t,b,n] = relu( sum_p S[n,p,t] * W[p,n,b] ) -------
#define TT 8
__global__ __launch_bounds__(256) void kc_out(const float* __restrict__ theta,
    const float* __restrict__ ck, const float* __restrict__ ps,
    float* __restrict__ out) {
  __shared__ __align__(16) float S[TT*120];     // [tt][n][12] padded
  __shared__ float C[300];
  __shared__ __align__(16) float stg[2][2560];  // double-buffered store stage
  const int tid = threadIdx.x;
  const int t0 = blockIdx.x * TT;
  const int b  = blockIdx.y * 256 + tid;
  for (int j = tid; j < 300; j += 256) C[j] = ck[j];
  for (int j = tid; j < TT*100; j += 256) {
    const int tt = j / 100, q = j - tt*100;
    float s = 0.f;
    #pragma unroll
    for (int sl = 0; sl < 8; ++sl)
      s += ps[((size_t)sl*TLEN + (t0+tt))*100 + q];
    S[tt*120 + (q/10)*12 + (q - (q/10)*10)] = s;
  }
  __syncthreads();
  float W[10][10];
  #pragma unroll
  for (int p = 0; p < 10; ++p) {
    const float th0 = theta[          p*NB + b];
    const float th1 = theta[10*NB  +  p*NB + b];
    const float th2 = theta[20*NB  +  p*NB + b];
    #pragma unroll
    for (int nn = 0; nn < 10; ++nn)
      W[p][nn] = C[p*10+nn]*th0 + C[100+p*10+nn]*th1 + C[200+p*10+nn]*th2;
  }
  for (int tt = 0; tt < TT; ++tt) {
    float acc[10];
    #pragma unroll
    for (int nn = 0; nn < 10; ++nn) {
      const float4 s0 = *(const float4*)(S + tt*120 + nn*12);
      const float4 s1 = *(const float4*)(S + tt*120 + nn*12 + 4);
      const float2 s2 = *(const float2*)(S + tt*120 + nn*12 + 8);
      acc[nn] = s0.x*W[0][nn] + s0.y*W[1][nn] + s0.z*W[2][nn] + s0.w*W[3][nn]
              + s1.x*W[4][nn] + s1.y*W[5][nn] + s1.z*W[6][nn] + s1.w*W[7][nn]
              + s2.x*W[8][nn] + s2.y*W[9][nn];
    }
    float* sg = stg[tt & 1];
    #pragma unroll
    for (int nn = 0; nn < 10; ++nn)
      sg[tid*10 + nn] = fmaxf(acc[nn], 0.f);
    __syncthreads();
    const float4* sp = (const float4*)sg;
    float4* op = (float4*)(out + (size_t)(t0+tt)*(NB*NS)
                               + (size_t)blockIdx.y*2560);
    op[tid]       = sp[tid];
    op[tid + 256] = sp[tid + 256];
    if (tid < 128) op[tid + 512] = sp[tid + 512];
  }
}

extern "C" void kernel_launch(void* const* d_in, const int* in_sizes, int n_in,
                              void* d_out, int out_size, void* d_ws, size_t ws_size,
                              hipStream_t stream) {
  const float* x   = (const float*)d_in[0];  // (4096,1024,10)
  const float* adj = (const float*)d_in[1];  // (5,5)
  const float* sa  = (const float*)d_in[2];  // (1024,10,10)
  const float* th  = (const float*)d_in[3];  // (3,10,1024)
  float* out = (float*)d_out;
  float* ws  = (float*)d_ws;
  float* ck  = ws;                // 300 floats
  float* ps  = ws + 1024;         // 8*4096*100 floats = 13.1 MB
  hipLaunchKernelGGL(ka_reduce, dim3(TLEN/TB, 8), dim3(384), 0, stream,
                     x, sa, adj, ps, ck);
  hipLaunchKernelGGL(kc_out,    dim3(TLEN/TT, NB/256), dim3(256), 0, stream,
                     th, ck, ps, out);
}